// Round 7
// baseline (95.946 us; speedup 1.0000x reference)
//
#include <hip/hip_runtime.h>

#define N_SRC_C   100000
#define N_DST_C   50000
#define N_EDGES_C 800000
#define D_C       64
// h_neigh = (1-ALPHA)*HBar + ALPHA*mean   (stop_gradient identity in fwd)
#define ONE_MINUS_ALPHA 0.9f
#define ALPHA_C        0.1f

#define CONV_ITEMS (N_SRC_C * D_C / 4)          // 1,600,000 float4 -> ushort4
#define PREP_BLOCKS ((CONV_ITEMS + 255) / 256)  // 6250

// ---------------------------------------------------------------------------
// Fused prep kernel: (1) H_src f32 -> bf16 table, (2) CSR row_ptr from sorted
// dst_idx, (3) W transpose to k-major.
// ---------------------------------------------------------------------------
__global__ __launch_bounds__(256) void prep_kernel(
    const float* __restrict__ H_src, ushort* __restrict__ Hb,
    const int* __restrict__ dst_idx, int* __restrict__ row_ptr,
    const float* __restrict__ W, float* __restrict__ WT)
{
    const int t = blockIdx.x * 256 + threadIdx.x;

    if (t < CONV_ITEMS) {                       // bf16 convert (RNE)
        const float4 v = reinterpret_cast<const float4*>(H_src)[t];
        ushort4 o; uint u;
        u = __float_as_uint(v.x); o.x = (ushort)((u + 0x7fffu + ((u >> 16) & 1u)) >> 16);
        u = __float_as_uint(v.y); o.y = (ushort)((u + 0x7fffu + ((u >> 16) & 1u)) >> 16);
        u = __float_as_uint(v.z); o.z = (ushort)((u + 0x7fffu + ((u >> 16) & 1u)) >> 16);
        u = __float_as_uint(v.w); o.w = (ushort)((u + 0x7fffu + ((u >> 16) & 1u)) >> 16);
        reinterpret_cast<ushort4*>(Hb)[t] = o;
    }

    if (t < N_EDGES_C) {                        // CSR row_ptr
        const int d = dst_idx[t];
        const int p = (t == 0) ? -1 : dst_idx[t - 1];
        for (int n = p + 1; n <= d; ++n) row_ptr[n] = t;
        if (t == N_EDGES_C - 1) {
            for (int n = d + 1; n <= N_DST_C; ++n) row_ptr[n] = N_EDGES_C;
        }
    }

    if (t < 64 * 128) {                         // W[64][128] -> WT[128][64]
        const int o = t >> 7, k = t & 127;
        WT[k * 64 + o] = W[t];
    }
}

// ---------------------------------------------------------------------------
// Mean kernel: 8 nodes per wave (group g = 8 lanes owns node wave*8+g; lane c
// owns features [8c,8c+8)). 16-deep gather batches: two idx registers preload
// 16 coalesced edge indices one iteration ahead; 16 back-to-back uint4
// gathers (8 x 128B rows per instruction) keep ~16 requests in flight per
// wave. Avg degree = 16 -> most groups finish in ONE iteration.
// ---------------------------------------------------------------------------
__global__ __launch_bounds__(256) void sage_mean_kernel(
    const ushort* __restrict__ Hb,       // bf16 H_src [N_SRC][64]
    const float*  __restrict__ HBar,
    const int*    __restrict__ src_idx,
    const int*    __restrict__ row_ptr,
    float*        __restrict__ h_neigh_out)  // [N_DST][64]
{
    const int lane = threadIdx.x & 63;
    const int g    = lane >> 3;                        // node slot 0..7
    const int c    = lane & 7;                         // feature chunk
    const int wave = blockIdx.x * 4 + (threadIdx.x >> 6);
    const int node = wave * 8 + g;                     // 50000/8 = 6250 waves exact

    const int s0 = row_ptr[node];
    const int s1 = row_ptr[node + 1];

    float acc[8];
    #pragma unroll
    for (int i = 0; i < 8; ++i) acc[i] = 0.f;

    // preload 16 idx (lane c of the group holds edges e+c and e+8+c, clamped)
    int idxA = 0, idxB = 0;
    if (s0 < s1) {
        int pA = s0 + c;     if (pA >= s1) pA = s1 - 1;
        int pB = s0 + 8 + c; if (pB >= s1) pB = s1 - 1;
        idxA = src_idx[pA];
        idxB = src_idx[pB];
    }

    for (int e = s0; e < s1; e += 16) {
        int nA = 0, nB = 0;
        if (e + 16 < s1) {
            int pA = e + 16 + c; if (pA >= s1) pA = s1 - 1;
            int pB = e + 24 + c; if (pB >= s1) pB = s1 - 1;
            nA = src_idx[pA];
            nB = src_idx[pB];
        }
        #pragma unroll
        for (int j = 0; j < 8; ++j) {
            const int ij = __shfl(idxA, g * 8 + j);
            if (e + j < s1) {
                const uint4 p = *reinterpret_cast<const uint4*>(
                    Hb + (size_t)ij * D_C + c * 8);
                acc[0] += __uint_as_float(p.x << 16);
                acc[1] += __uint_as_float(p.x & 0xffff0000u);
                acc[2] += __uint_as_float(p.y << 16);
                acc[3] += __uint_as_float(p.y & 0xffff0000u);
                acc[4] += __uint_as_float(p.z << 16);
                acc[5] += __uint_as_float(p.z & 0xffff0000u);
                acc[6] += __uint_as_float(p.w << 16);
                acc[7] += __uint_as_float(p.w & 0xffff0000u);
            }
        }
        #pragma unroll
        for (int j = 0; j < 8; ++j) {
            const int ij = __shfl(idxB, g * 8 + j);
            if (e + 8 + j < s1) {
                const uint4 p = *reinterpret_cast<const uint4*>(
                    Hb + (size_t)ij * D_C + c * 8);
                acc[0] += __uint_as_float(p.x << 16);
                acc[1] += __uint_as_float(p.x & 0xffff0000u);
                acc[2] += __uint_as_float(p.y << 16);
                acc[3] += __uint_as_float(p.y & 0xffff0000u);
                acc[4] += __uint_as_float(p.z << 16);
                acc[5] += __uint_as_float(p.z & 0xffff0000u);
                acc[6] += __uint_as_float(p.w << 16);
                acc[7] += __uint_as_float(p.w & 0xffff0000u);
            }
        }
        idxA = nA; idxB = nB;
    }

    const int cnt = s1 - s0;
    const float inv = (cnt > 0) ? (ALPHA_C / (float)cnt) : 0.0f;

    const size_t base = (size_t)node * D_C + c * 8;
    const float4 hb0 = *reinterpret_cast<const float4*>(HBar + base);
    const float4 hb1 = *reinterpret_cast<const float4*>(HBar + base + 4);
    float4 o0, o1;
    o0.x = ONE_MINUS_ALPHA * hb0.x + acc[0] * inv;
    o0.y = ONE_MINUS_ALPHA * hb0.y + acc[1] * inv;
    o0.z = ONE_MINUS_ALPHA * hb0.z + acc[2] * inv;
    o0.w = ONE_MINUS_ALPHA * hb0.w + acc[3] * inv;
    o1.x = ONE_MINUS_ALPHA * hb1.x + acc[4] * inv;
    o1.y = ONE_MINUS_ALPHA * hb1.y + acc[5] * inv;
    o1.z = ONE_MINUS_ALPHA * hb1.z + acc[6] * inv;
    o1.w = ONE_MINUS_ALPHA * hb1.w + acc[7] * inv;
    *reinterpret_cast<float4*>(h_neigh_out + base)     = o0;
    *reinterpret_cast<float4*>(h_neigh_out + base + 4) = o1;
}

// ---------------------------------------------------------------------------
// Linear kernel v3: lane = output o, W row in VGPRs (coalesced fill from
// k-major WT). Per block: stage a 64-node X-tile = [64][32] float4 (32KB LDS,
// coalesced global loads), then wave q computes nodes [16q,16q+16) reading x
// via wave-uniform ds_read_b128 broadcasts (conflict-free, full rate).
// Replaces the slow scalar-pipe x-streaming (constant-$ latency exposed).
// ---------------------------------------------------------------------------
__global__ __launch_bounds__(256) void sage_linear_kernel(
    const float* __restrict__ H_dst,
    const float* __restrict__ h_neigh,
    const float* __restrict__ WT,        // [128][64] k-major
    const float* __restrict__ b,
    float*       __restrict__ h_out)     // [N_DST][64]
{
    __shared__ __align__(16) float4 Xs[64 * 32];   // [node][k4]; k4<16 H_dst, >=16 h_neigh

    const int lane = threadIdx.x & 63;
    const int q    = threadIdx.x >> 6;

    float wreg[128];
    #pragma unroll
    for (int k = 0; k < 128; ++k) wreg[k] = WT[k * 64 + lane];  // coalesced
    const float bias = b[lane];

    const int tile = blockIdx.x * 64;

    // stage: 1024 iterations cover 64 rows x 16 chunks; 2 loads each
    for (int i = threadIdx.x; i < 1024; i += 256) {
        const int r = i >> 4, c4 = i & 15;
        int n = tile + r; if (n > N_DST_C - 1) n = N_DST_C - 1;
        Xs[r * 32 + c4]      = *reinterpret_cast<const float4*>(H_dst   + (size_t)n * D_C + c4 * 4);
        Xs[r * 32 + 16 + c4] = *reinterpret_cast<const float4*>(h_neigh + (size_t)n * D_C + c4 * 4);
    }
    __syncthreads();

    for (int nn = 0; nn < 16; ++nn) {
        int node = tile + q * 16 + nn;
        if (node > N_DST_C - 1) node = N_DST_C - 1;   // duplicate identical writes
        const float4* __restrict__ xrow = &Xs[(q * 16 + nn) * 32];
        float a0 = 0.f, a1 = 0.f, a2 = 0.f, a3 = 0.f;
        #pragma unroll
        for (int k4 = 0; k4 < 32; ++k4) {
            const float4 xv = xrow[k4];               // uniform addr -> broadcast
            a0 = fmaf(wreg[k4 * 4 + 0], xv.x, a0);
            a1 = fmaf(wreg[k4 * 4 + 1], xv.y, a1);
            a2 = fmaf(wreg[k4 * 4 + 2], xv.z, a2);
            a3 = fmaf(wreg[k4 * 4 + 3], xv.w, a3);
        }
        h_out[(size_t)node * D_C + lane] = fmaxf(bias + ((a0 + a1) + (a2 + a3)), 0.0f);
    }
}

// ---------------------------------------------------------------------------
extern "C" void kernel_launch(void* const* d_in, const int* in_sizes, int n_in,
                              void* d_out, int out_size, void* d_ws, size_t ws_size,
                              hipStream_t stream) {
    const float* H_src   = (const float*)d_in[0];
    const float* H_dst   = (const float*)d_in[1];
    const float* HBar    = (const float*)d_in[2];
    const int*   src_idx = (const int*)d_in[3];
    const int*   dst_idx = (const int*)d_in[4];
    const float* W       = (const float*)d_in[5];
    const float* b       = (const float*)d_in[6];

    float* out    = (float*)d_out;
    float* h_out  = out;                             // [N_DST][64]
    float* hn_out = out + (size_t)N_DST_C * D_C;     // [N_DST][64]

    // ws layout: row_ptr @0 (200KB), WT @256KB (32KB), Hb @512KB (12.8MB)
    int*    row_ptr = (int*)d_ws;
    float*  WT      = (float*)((char*)d_ws + (256 << 10));
    ushort* Hb      = (ushort*)((char*)d_ws + (512 << 10));

    hipLaunchKernelGGL(prep_kernel, dim3(PREP_BLOCKS), dim3(256), 0, stream,
                       H_src, Hb, dst_idx, row_ptr, W, WT);

    // 8 nodes/wave, 4 waves/block -> 32 nodes/block; 50000/32 -> 1563 blocks
    hipLaunchKernelGGL(sage_mean_kernel, dim3((N_DST_C + 31) / 32), dim3(256), 0, stream,
                       Hb, HBar, src_idx, row_ptr, hn_out);

    // 64-node tiles
    hipLaunchKernelGGL(sage_linear_kernel, dim3((N_DST_C + 63) / 64), dim3(256), 0, stream,
                       H_dst, hn_out, WT, b, h_out);
}

// Round 9
// 36.917 us; speedup vs baseline: 2.5990x; 2.5990x over previous
//
#include <hip/hip_runtime.h>

#define N_SRC_C   100000
#define N_DST_C   50000
#define N_EDGES_C 800000
#define D_C       64
// h_neigh = (1-ALPHA)*HBar + ALPHA*mean   (stop_gradient identity in fwd)
#define ONE_MINUS_ALPHA 0.9f
#define ALPHA_C        0.1f

#define CONV_ITEMS (N_SRC_C * D_C / 4)          // 1,600,000 float4 -> ushort4
#define PREP_BLOCKS ((CONV_ITEMS + 255) / 256)  // 6250

typedef __attribute__((ext_vector_type(8))) short bf16x8;
typedef __attribute__((ext_vector_type(4))) float f32x4;

__device__ __forceinline__ ushort f32_to_bf16(float f) {
    uint u = __float_as_uint(f);
    return (ushort)((u + 0x7fffu + ((u >> 16) & 1u)) >> 16);
}

// ---------------------------------------------------------------------------
// Prep: (1) H_src f32->bf16 gather table, (2) CSR row_ptr from sorted dst_idx,
// (3) W packed into MFMA B-fragment layout:
//     WB[((ob*4+ks)*64+lane)*8+j] = bf16(W[ob*16+(lane&15)][ks*32+(lane>>4)*8+j])
// (prep->consumer dependency pattern identical to R5-R7, which passed replay.)
// ---------------------------------------------------------------------------
__global__ __launch_bounds__(256) void prep_kernel(
    const float* __restrict__ H_src, ushort* __restrict__ Hb,
    const int* __restrict__ dst_idx, int* __restrict__ row_ptr,
    const float* __restrict__ W, ushort* __restrict__ WB)
{
    const int t = blockIdx.x * 256 + threadIdx.x;

    if (t < CONV_ITEMS) {                       // H_src -> bf16 (RNE)
        const float4 v = reinterpret_cast<const float4*>(H_src)[t];
        ushort4 o;
        o.x = f32_to_bf16(v.x); o.y = f32_to_bf16(v.y);
        o.z = f32_to_bf16(v.z); o.w = f32_to_bf16(v.w);
        reinterpret_cast<ushort4*>(Hb)[t] = o;
    }

    if (t < N_EDGES_C) {                        // CSR row_ptr
        const int d = dst_idx[t];
        const int p = (t == 0) ? -1 : dst_idx[t - 1];
        for (int n = p + 1; n <= d; ++n) row_ptr[n] = t;
        if (t == N_EDGES_C - 1) {
            for (int n = d + 1; n <= N_DST_C; ++n) row_ptr[n] = N_EDGES_C;
        }
    }

    if (t < 4 * 4 * 64 * 8) {                   // W -> B-fragment pack (16KB)
        const int j    = t & 7;
        const int lane = (t >> 3) & 63;
        const int ks   = (t >> 9) & 3;
        const int ob   = t >> 11;
        const int o = ob * 16 + (lane & 15);
        const int k = ks * 32 + ((lane >> 4) << 3) + j;
        WB[t] = f32_to_bf16(W[o * 128 + k]);
    }
}

// ---------------------------------------------------------------------------
// FUSED mean + linear. Block = 256 threads = 4 waves = 32 nodes.
// Phase 1 (per wave, 8 nodes: group g owns node base+w*8+g, lane c owns
//   features [8c,8c+8)): 16-deep batched gather of bf16 H_src rows with
//   indices preloaded coalesced one iteration ahead (shfl-distributed);
//   CV-blend; write f32 h_neigh to d_out; stage bf16 X row halves into LDS
//   ([H_dst | h_neigh], padded stride 136 -> <=2-way bank aliasing = free).
// Phase 2 (after __syncthreads): wave w -> tile (w>>1) of 16 nodes, output
//   blocks {2(w&1), 2(w&1)+1}; 8x mfma_f32_16x16x32_bf16; bias+relu; store.
// Tail block: clamp node -> duplicate IDENTICAL writes (deterministic).
// No cross-kernel tensor handoff except prep's (R5-R7-proven safe).
// ---------------------------------------------------------------------------
__global__ __launch_bounds__(256) void sage_fused_kernel(
    const ushort* __restrict__ Hb,       // bf16 H_src [N_SRC][64]
    const float*  __restrict__ H_dst,
    const float*  __restrict__ HBar,
    const int*    __restrict__ src_idx,
    const int*    __restrict__ row_ptr,
    const ushort* __restrict__ WB,       // packed B-frags [4][4][64][8] bf16
    const float*  __restrict__ b,        // [64]
    float*        __restrict__ h_out,    // [N_DST][64] f32
    float*        __restrict__ hn_out)   // [N_DST][64] f32
{
    __shared__ __align__(16) ushort Xs[32][136];   // 8.7KB, 136 = 128 + 8 pad

    const int lane = threadIdx.x & 63;
    const int w    = threadIdx.x >> 6;
    const int g    = lane >> 3;                    // node slot 0..7
    const int c    = lane & 7;                     // feature chunk
    const int base = blockIdx.x * 32;
    const int r    = w * 8 + g;                    // local X row 0..31
    int node = base + r;
    if (node > N_DST_C - 1) node = N_DST_C - 1;    // tail: duplicate identical work

    const int s0 = row_ptr[node];
    const int s1 = row_ptr[node + 1];

    float acc[8];
    #pragma unroll
    for (int i = 0; i < 8; ++i) acc[i] = 0.f;

    // preload 16 edge indices (lane c holds edges e+c, e+8+c, clamped)
    int idxA = 0, idxB = 0;
    if (s0 < s1) {
        int pA = s0 + c;     if (pA >= s1) pA = s1 - 1;
        int pB = s0 + 8 + c; if (pB >= s1) pB = s1 - 1;
        idxA = src_idx[pA];
        idxB = src_idx[pB];
    }

    for (int e = s0; e < s1; e += 16) {
        int nA = 0, nB = 0;
        if (e + 16 < s1) {
            int pA = e + 16 + c; if (pA >= s1) pA = s1 - 1;
            int pB = e + 24 + c; if (pB >= s1) pB = s1 - 1;
            nA = src_idx[pA];
            nB = src_idx[pB];
        }
        #pragma unroll
        for (int j = 0; j < 8; ++j) {
            const int ij = __shfl(idxA, g * 8 + j);
            if (e + j < s1) {
                const uint4 p = *reinterpret_cast<const uint4*>(
                    Hb + (size_t)ij * D_C + c * 8);
                acc[0] += __uint_as_float(p.x << 16);
                acc[1] += __uint_as_float(p.x & 0xffff0000u);
                acc[2] += __uint_as_float(p.y << 16);
                acc[3] += __uint_as_float(p.y & 0xffff0000u);
                acc[4] += __uint_as_float(p.z << 16);
                acc[5] += __uint_as_float(p.z & 0xffff0000u);
                acc[6] += __uint_as_float(p.w << 16);
                acc[7] += __uint_as_float(p.w & 0xffff0000u);
            }
        }
        #pragma unroll
        for (int j = 0; j < 8; ++j) {
            const int ij = __shfl(idxB, g * 8 + j);
            if (e + 8 + j < s1) {
                const uint4 p = *reinterpret_cast<const uint4*>(
                    Hb + (size_t)ij * D_C + c * 8);
                acc[0] += __uint_as_float(p.x << 16);
                acc[1] += __uint_as_float(p.x & 0xffff0000u);
                acc[2] += __uint_as_float(p.y << 16);
                acc[3] += __uint_as_float(p.y & 0xffff0000u);
                acc[4] += __uint_as_float(p.z << 16);
                acc[5] += __uint_as_float(p.z & 0xffff0000u);
                acc[6] += __uint_as_float(p.w << 16);
                acc[7] += __uint_as_float(p.w & 0xffff0000u);
            }
        }
        idxA = nA; idxB = nB;
    }

    const int cnt = s1 - s0;
    const float inv = (cnt > 0) ? (ALPHA_C / (float)cnt) : 0.0f;

    const size_t hbase = (size_t)node * D_C + c * 8;
    const float4 hb0 = *reinterpret_cast<const float4*>(HBar + hbase);
    const float4 hb1 = *reinterpret_cast<const float4*>(HBar + hbase + 4);
    float o[8];
    o[0] = ONE_MINUS_ALPHA * hb0.x + acc[0] * inv;
    o[1] = ONE_MINUS_ALPHA * hb0.y + acc[1] * inv;
    o[2] = ONE_MINUS_ALPHA * hb0.z + acc[2] * inv;
    o[3] = ONE_MINUS_ALPHA * hb0.w + acc[3] * inv;
    o[4] = ONE_MINUS_ALPHA * hb1.x + acc[4] * inv;
    o[5] = ONE_MINUS_ALPHA * hb1.y + acc[5] * inv;
    o[6] = ONE_MINUS_ALPHA * hb1.z + acc[6] * inv;
    o[7] = ONE_MINUS_ALPHA * hb1.w + acc[7] * inv;

    *reinterpret_cast<float4*>(hn_out + hbase)     = make_float4(o[0], o[1], o[2], o[3]);
    *reinterpret_cast<float4*>(hn_out + hbase + 4) = make_float4(o[4], o[5], o[6], o[7]);

    // stage X row r: high half (h_neigh) from registers, low half from H_dst
    union { ushort u[8]; bf16x8 v; } hi, lo;
    #pragma unroll
    for (int i = 0; i < 8; ++i) hi.u[i] = f32_to_bf16(o[i]);
    *reinterpret_cast<bf16x8*>(&Xs[r][64 + c * 8]) = hi.v;

    const float4 d0 = *reinterpret_cast<const float4*>(H_dst + hbase);
    const float4 d1 = *reinterpret_cast<const float4*>(H_dst + hbase + 4);
    lo.u[0] = f32_to_bf16(d0.x); lo.u[1] = f32_to_bf16(d0.y);
    lo.u[2] = f32_to_bf16(d0.z); lo.u[3] = f32_to_bf16(d0.w);
    lo.u[4] = f32_to_bf16(d1.x); lo.u[5] = f32_to_bf16(d1.y);
    lo.u[6] = f32_to_bf16(d1.z); lo.u[7] = f32_to_bf16(d1.w);
    *reinterpret_cast<bf16x8*>(&Xs[r][c * 8]) = lo.v;

    __syncthreads();

    // ---- MFMA phase: wave w -> tile (w>>1), output blocks ob0, ob0+1 ----
    const int tile  = w >> 1;
    const int ob0   = (w & 1) * 2;
    const int row16 = lane & 15;
    const int kg    = lane >> 4;

    bf16x8 af[4];
    #pragma unroll
    for (int ks = 0; ks < 4; ++ks)
        af[ks] = *reinterpret_cast<const bf16x8*>(&Xs[tile * 16 + row16][kg * 8 + ks * 32]);

    #pragma unroll
    for (int oi = 0; oi < 2; ++oi) {
        const int ob = ob0 + oi;
        f32x4 cacc = {0.f, 0.f, 0.f, 0.f};
        #pragma unroll
        for (int ks = 0; ks < 4; ++ks) {
            const bf16x8 bf = *reinterpret_cast<const bf16x8*>(
                WB + ((size_t)(ob * 4 + ks) * 64 + lane) * 8);
            cacc = __builtin_amdgcn_mfma_f32_16x16x32_bf16(af[ks], bf, cacc, 0, 0, 0);
        }
        const float bias = b[ob * 16 + row16];
        #pragma unroll
        for (int rr = 0; rr < 4; ++rr) {
            int gn = base + tile * 16 + kg * 4 + rr;
            if (gn > N_DST_C - 1) gn = N_DST_C - 1;   // duplicate identical value
            h_out[(size_t)gn * D_C + ob * 16 + row16] = fmaxf(cacc[rr] + bias, 0.0f);
        }
    }
}

// ---------------------------------------------------------------------------
extern "C" void kernel_launch(void* const* d_in, const int* in_sizes, int n_in,
                              void* d_out, int out_size, void* d_ws, size_t ws_size,
                              hipStream_t stream) {
    const float* H_src   = (const float*)d_in[0];
    const float* H_dst   = (const float*)d_in[1];
    const float* HBar    = (const float*)d_in[2];
    const int*   src_idx = (const int*)d_in[3];
    const int*   dst_idx = (const int*)d_in[4];
    const float* W       = (const float*)d_in[5];
    const float* b       = (const float*)d_in[6];

    float* out    = (float*)d_out;
    float* h_out  = out;                             // [N_DST][64]
    float* hn_out = out + (size_t)N_DST_C * D_C;     // [N_DST][64]

    // ws: row_ptr @0 (200KB), WB @256KB (16KB), Hb @512KB (12.8MB)
    int*    row_ptr = (int*)d_ws;
    ushort* WB      = (ushort*)((char*)d_ws + (256 << 10));
    ushort* Hb      = (ushort*)((char*)d_ws + (512 << 10));

    hipLaunchKernelGGL(prep_kernel, dim3(PREP_BLOCKS), dim3(256), 0, stream,
                       H_src, Hb, dst_idx, row_ptr, W, WB);

    // 32 nodes/block -> 1563 blocks (tail clamped)
    hipLaunchKernelGGL(sage_fused_kernel, dim3((N_DST_C + 31) / 32), dim3(256), 0, stream,
                       Hb, H_dst, HBar, src_idx, row_ptr, WB, b, h_out, hn_out);
}